// Round 1
// baseline (326.931 us; speedup 1.0000x reference)
//
#include <hip/hip_runtime.h>
#include <hip/hip_bf16.h>

#define DIM   128
#define HEADS 4
#define HD    32
#define NTOK  49
#define BWIN  4096
#define SCALE 0.17677669529663687f

typedef __attribute__((ext_vector_type(8))) short bf16x8;
typedef __attribute__((ext_vector_type(4))) float f32x4;

__device__ inline short cvt_bf16(float f) {
    union { float f; unsigned u; } v; v.f = f;
    unsigned r = v.u + 0x7fffu + ((v.u >> 16) & 1u);
    return (short)(r >> 16);
}

// ws layout (short elements):
//   [0, 32768)        W_kv^T  bf16 [256][128]
//   [32768, 49152)    W_proj^T bf16 [128][128]
//   [49152, 450560)   q bf16 * SCALE, [64 img][4 h][49 n][32 d]
//   byte 901120..     bias fp32 [4 h][49 i][49 j]
#define WS_WPT  32768
#define WS_QW   49152
#define WS_BIAS 450560   // short offset; cast to float*

__global__ void prep_kernel(const float* __restrict__ qg,
                            const float* __restrict__ rbt,
                            const float* __restrict__ wkv,
                            const float* __restrict__ wpj,
                            const int*   __restrict__ ridx,
                            short* __restrict__ ws) {
    int i = blockIdx.x * 256 + threadIdx.x;
    if (i < 32768) {                       // W_kv^T
        int c = i >> 7, k = i & 127;
        ws[i] = cvt_bf16(wkv[k * 256 + c]);
        return;
    }
    i -= 32768;
    if (i < 16384) {                       // W_proj^T
        int c = i >> 7, k = i & 127;
        ws[WS_WPT + i] = cvt_bf16(wpj[k * 128 + c]);
        return;
    }
    i -= 16384;
    if (i < 401408) {                      // q * SCALE
        ws[WS_QW + i] = cvt_bf16(qg[i] * SCALE);
        return;
    }
    i -= 401408;
    if (i < 9604) {                        // bias gather [h][i][j]
        int h = i / 2401, r = i % 2401;
        float* bias = (float*)(ws + WS_BIAS);
        bias[i] = rbt[ridx[r] * HEADS + h];
    }
}

// LDS (short elements):
//  ks  [4][64][40]  @ 0       (k, row-major per head, d-padded 32->40)
//  vts [4][32][72]  @ 10240   (v transposed per head [d][tok], tok-padded 64->72)
//  ps  [4][64][72]  @ 19456   (softmax probs per head)
//  os  [64][136]    @ 0       (overlay on ks+vts; O concat for proj)
__global__ __launch_bounds__(256, 2) void win_attn_kernel(
        const float* __restrict__ x,
        const short* __restrict__ ws,
        const float* __restrict__ bkv,
        const float* __restrict__ bpj,
        float* __restrict__ out) {
    const int b    = blockIdx.x;
    const int img  = b >> 6;
    const int tid  = threadIdx.x;
    const int w    = tid >> 6;
    const int lane = tid & 63;
    const int quad = lane >> 4;
    const int l16  = lane & 15;

    const short* wkvt  = ws;
    const short* wpt   = ws + WS_WPT;
    const short* qw    = ws + WS_QW;
    const float* biasg = (const float*)(ws + WS_BIAS);

    __shared__ __align__(16) short smem[37888];
    short* ks  = smem;
    short* vts = smem + 10240;
    short* ps  = smem + 19456;
    short* os  = smem;

    const f32x4 fzero = {0.f, 0.f, 0.f, 0.f};

    // ---------------- Stage 1: kv = x[b] @ W_kv + b_kv ----------------
    bf16x8 afrag[4][4];                       // [mi][kstep]
    const float* xb = x + (long)b * NTOK * DIM;
    for (int mi = 0; mi < 4; ++mi) {
        int tok = mi * 16 + l16; if (tok > 48) tok = 48;
        for (int kk = 0; kk < 4; ++kk) {
            const float* xr = xb + tok * DIM + kk * 32 + quad * 8;
            float4 a = *(const float4*)xr;
            float4 c = *(const float4*)(xr + 4);
            bf16x8 f;
            f[0] = cvt_bf16(a.x); f[1] = cvt_bf16(a.y);
            f[2] = cvt_bf16(a.z); f[3] = cvt_bf16(a.w);
            f[4] = cvt_bf16(c.x); f[5] = cvt_bf16(c.y);
            f[6] = cvt_bf16(c.z); f[7] = cvt_bf16(c.w);
            afrag[mi][kk] = f;
        }
    }

    for (int nt = 0; nt < 4; ++nt) {
        const int c0 = (w * 4 + nt) * 16;
        f32x4 acc[4] = {fzero, fzero, fzero, fzero};
        for (int kk = 0; kk < 4; ++kk) {
            bf16x8 bfrag = *(const bf16x8*)(wkvt + (c0 + l16) * DIM + kk * 32 + quad * 8);
            for (int mi = 0; mi < 4; ++mi)
                acc[mi] = __builtin_amdgcn_mfma_f32_16x16x32_bf16(afrag[mi][kk], bfrag, acc[mi], 0, 0, 0);
        }
        const int c = c0 + l16;
        const float bias = bkv[c];
        for (int mi = 0; mi < 4; ++mi) {
            for (int r = 0; r < 4; ++r) {
                int tok = mi * 16 + quad * 4 + r;
                short val = cvt_bf16(acc[mi][r] + bias);
                if (c < 128) {
                    int h = c >> 5, d = c & 31;
                    ks[(h * 64 + tok) * 40 + d] = val;
                } else {
                    int cv = c - 128;
                    int h = cv >> 5, d = cv & 31;
                    vts[(h * 32 + d) * 72 + tok] = val;
                }
            }
        }
    }
    __syncthreads();

    // ---------------- Stage 2: S = q @ k^T + bias, softmax ----------------
    const int h = w;
    const short* qh = qw + (long)(img * HEADS + h) * NTOK * HD;
    bf16x8 qfrag[4];
    for (int mi = 0; mi < 4; ++mi) {
        int tok = mi * 16 + l16; if (tok > 48) tok = 48;
        qfrag[mi] = *(const bf16x8*)(qh + tok * HD + quad * 8);
    }
    f32x4 sacc[4][4];
    for (int mi = 0; mi < 4; ++mi)
        for (int ni = 0; ni < 4; ++ni) sacc[mi][ni] = fzero;
    for (int ni = 0; ni < 4; ++ni) {
        bf16x8 kfrag = *(const bf16x8*)(ks + (h * 64 + ni * 16 + l16) * 40 + quad * 8);
        for (int mi = 0; mi < 4; ++mi)
            sacc[mi][ni] = __builtin_amdgcn_mfma_f32_16x16x32_bf16(qfrag[mi], kfrag, sacc[mi][ni], 0, 0, 0);
    }

    const float* bh = biasg + h * 2401;
    for (int mi = 0; mi < 4; ++mi) {
        for (int r = 0; r < 4; ++r) {
            int i = mi * 16 + quad * 4 + r;
            int ic = i > 48 ? 48 : i;
            float vals[4];
            for (int ni = 0; ni < 4; ++ni) {
                int j = ni * 16 + l16;
                float sv = sacc[mi][ni][r];
                if (j < NTOK) sv += bh[ic * 49 + j];
                else          sv = -1e30f;
                vals[ni] = sv;
            }
            float m = fmaxf(fmaxf(vals[0], vals[1]), fmaxf(vals[2], vals[3]));
            for (int off = 1; off < 16; off <<= 1)
                m = fmaxf(m, __shfl_xor(m, off, 64));
            float s = 0.f;
            for (int ni = 0; ni < 4; ++ni) {
                float e = (vals[ni] > -1e29f) ? __expf(vals[ni] - m) : 0.f;
                vals[ni] = e; s += e;
            }
            for (int off = 1; off < 16; off <<= 1)
                s += __shfl_xor(s, off, 64);
            float inv = 1.0f / s;
            for (int ni = 0; ni < 4; ++ni) {
                int j = ni * 16 + l16;
                ps[(h * 64 + i) * 72 + j] = cvt_bf16(vals[ni] * inv);
            }
        }
    }

    // ---------------- Stage 3: O = P @ V ----------------
    f32x4 oacc[4][2];
    for (int mi = 0; mi < 4; ++mi)
        for (int nt = 0; nt < 2; ++nt) oacc[mi][nt] = fzero;
    for (int kk = 0; kk < 2; ++kk) {
        bf16x8 pfrag[4];
        for (int mi = 0; mi < 4; ++mi)
            pfrag[mi] = *(const bf16x8*)(ps + (h * 64 + mi * 16 + l16) * 72 + kk * 32 + quad * 8);
        for (int nt = 0; nt < 2; ++nt) {
            bf16x8 vfrag = *(const bf16x8*)(vts + (h * 32 + nt * 16 + l16) * 72 + kk * 32 + quad * 8);
            for (int mi = 0; mi < 4; ++mi)
                oacc[mi][nt] = __builtin_amdgcn_mfma_f32_16x16x32_bf16(pfrag[mi], vfrag, oacc[mi][nt], 0, 0, 0);
        }
    }
    __syncthreads();   // everyone done reading vts/ps regions that os overlays

    for (int mi = 0; mi < 4; ++mi)
        for (int nt = 0; nt < 2; ++nt)
            for (int r = 0; r < 4; ++r) {
                int tok = mi * 16 + quad * 4 + r;
                os[tok * 136 + h * 32 + nt * 16 + l16] = cvt_bf16(oacc[mi][nt][r]);
            }
    __syncthreads();

    // ---------------- Stage 4: out = O @ W_proj + b_proj ----------------
    bf16x8 ofrag[4][4];
    for (int mi = 0; mi < 4; ++mi)
        for (int kk = 0; kk < 4; ++kk)
            ofrag[mi][kk] = *(const bf16x8*)(os + (mi * 16 + l16) * 136 + kk * 32 + quad * 8);
    for (int ct = 0; ct < 2; ++ct) {
        const int c0 = (w * 2 + ct) * 16;
        f32x4 pacc[4] = {fzero, fzero, fzero, fzero};
        for (int kk = 0; kk < 4; ++kk) {
            bf16x8 wfrag = *(const bf16x8*)(wpt + (c0 + l16) * DIM + kk * 32 + quad * 8);
            for (int mi = 0; mi < 4; ++mi)
                pacc[mi] = __builtin_amdgcn_mfma_f32_16x16x32_bf16(ofrag[mi][kk], wfrag, pacc[mi], 0, 0, 0);
        }
        const float bb = bpj[c0 + l16];
        for (int mi = 0; mi < 4; ++mi)
            for (int r = 0; r < 4; ++r) {
                int tok = mi * 16 + quad * 4 + r;
                if (tok < NTOK)
                    out[((long)b * NTOK + tok) * DIM + c0 + l16] = pacc[mi][r] + bb;
            }
    }
}

extern "C" void kernel_launch(void* const* d_in, const int* in_sizes, int n_in,
                              void* d_out, int out_size, void* d_ws, size_t ws_size,
                              hipStream_t stream) {
    const float* x   = (const float*)d_in[0];
    const float* qg  = (const float*)d_in[1];
    const float* rbt = (const float*)d_in[2];
    const float* wkv = (const float*)d_in[3];
    const float* bkv = (const float*)d_in[4];
    const float* wpj = (const float*)d_in[5];
    const float* bpj = (const float*)d_in[6];
    const int*   ridx = (const int*)d_in[7];
    short* ws = (short*)d_ws;

    const int prep_total = 32768 + 16384 + 401408 + 9604;
    prep_kernel<<<(prep_total + 255) / 256, 256, 0, stream>>>(qg, rbt, wkv, wpj, ridx, ws);
    win_attn_kernel<<<BWIN, 256, 0, stream>>>(x, ws, bkv, bpj, (float*)d_out);
}

// Round 2
// 309.792 us; speedup vs baseline: 1.0553x; 1.0553x over previous
//
#include <hip/hip_runtime.h>

#define SCALE 0.17677669529663687f

typedef __attribute__((ext_vector_type(8))) short bf16x8;
typedef __attribute__((ext_vector_type(4))) float f32x4;

__device__ inline short cvt_bf16(float f) {
    union { float f; unsigned u; } v; v.f = f;
    unsigned r = v.u + 0x7fffu + ((v.u >> 16) & 1u);
    return (short)(r >> 16);
}

// ws layout (short elements):
//   [0, 32768)        W_kv^T  bf16 [256][128]
//   [32768, 49152)    W_proj^T bf16 [128][128]
//   [49152, 450560)   q bf16 * SCALE, [64 img][4 h][49 n][32 d]
//   short 450560..    bias fp32 [4 h][49 i][64 jpad]  (~50 KB)
#define WS_WPT  32768
#define WS_QW   49152
#define WS_BIAS 450560

__global__ void prep_kernel(const float* __restrict__ qg,
                            const float* __restrict__ rbt,
                            const float* __restrict__ wkv,
                            const float* __restrict__ wpj,
                            const int*   __restrict__ ridx,
                            short* __restrict__ ws) {
    int i = blockIdx.x * 256 + threadIdx.x;
    if (i < 32768) {                       // W_kv^T
        int c = i >> 7, k = i & 127;
        ws[i] = cvt_bf16(wkv[k * 256 + c]);
        return;
    }
    i -= 32768;
    if (i < 16384) {                       // W_proj^T
        int c = i >> 7, k = i & 127;
        ws[WS_WPT + i] = cvt_bf16(wpj[k * 128 + c]);
        return;
    }
    i -= 16384;
    if (i < 100352) {                      // q * SCALE, 4 elems/thread
        float4 q4 = *(const float4*)(qg + (long)i * 4);
        short p0 = cvt_bf16(q4.x * SCALE), p1 = cvt_bf16(q4.y * SCALE);
        short p2 = cvt_bf16(q4.z * SCALE), p3 = cvt_bf16(q4.w * SCALE);
        unsigned lo = (unsigned short)p0 | ((unsigned)(unsigned short)p1 << 16);
        unsigned hi = (unsigned short)p2 | ((unsigned)(unsigned short)p3 << 16);
        uint2 u; u.x = lo; u.y = hi;
        *(uint2*)(ws + WS_QW + (long)i * 4) = u;
        return;
    }
    i -= 100352;
    if (i < 12544) {                       // bias padded [h][i][64]
        int h = i / 3136, rem = i % 3136, ir = rem >> 6, j = rem & 63;
        float* bias = (float*)(ws + WS_BIAS);
        bias[i] = (j < 49) ? rbt[ridx[ir * 49 + j] * 4 + h] : 0.f;
    }
}

// LDS (shorts):
//  regA [4 slots of 3744]: ks[h] (64 rows x stride 40) overlaid by ps[h] (52 rows x stride 72)
//  vts  @15840: [4*32][72]  (V^T per head)
//  os   @0: [64][136] overlay for proj stage
#define SLOT    3744
#define VTS_OFF 15840
#define SMEM_SZ 25056

__global__ __launch_bounds__(256, 3) void win_attn_kernel(
        const float* __restrict__ x,
        const short* __restrict__ ws,
        const float* __restrict__ bkv,
        const float* __restrict__ bpj,
        float* __restrict__ out) {
    const int b    = blockIdx.x;
    const int img  = b >> 6;
    const int tid  = threadIdx.x;
    const int w    = tid >> 6;
    const int lane = tid & 63;
    const int quad = lane >> 4;
    const int l16  = lane & 15;

    const short* wkvt  = ws;
    const short* wpt   = ws + WS_WPT;
    const short* qw    = ws + WS_QW;
    const float* biasb = (const float*)(ws + WS_BIAS);

    __shared__ __align__(16) short smem[SMEM_SZ];
    short* regA = smem;
    short* vts  = smem + VTS_OFF;
    short* os   = smem;

    const f32x4 fzero = {0.f, 0.f, 0.f, 0.f};
    const int h = w;

    // ---------------- Stage 1: kv = x[b] @ W_kv + b_kv ----------------
    bf16x8 afrag[4][4];
    const float* xb = x + (long)b * 49 * 128;
    #pragma unroll
    for (int mi = 0; mi < 4; ++mi) {
        int tok = mi * 16 + l16; if (tok > 48) tok = 48;
        #pragma unroll
        for (int kk = 0; kk < 4; ++kk) {
            const float* xr = xb + tok * 128 + kk * 32 + quad * 8;
            float4 a = *(const float4*)xr;
            float4 c = *(const float4*)(xr + 4);
            bf16x8 f;
            f[0] = cvt_bf16(a.x); f[1] = cvt_bf16(a.y);
            f[2] = cvt_bf16(a.z); f[3] = cvt_bf16(a.w);
            f[4] = cvt_bf16(c.x); f[5] = cvt_bf16(c.y);
            f[6] = cvt_bf16(c.z); f[7] = cvt_bf16(c.w);
            afrag[mi][kk] = f;
        }
    }
    // prefetch q B-frags (global, independent of stage 1)
    const short* qh = qw + (long)(img * 4 + h) * 49 * 32;
    bf16x8 qfrag[4];
    #pragma unroll
    for (int ni = 0; ni < 4; ++ni) {
        int i = ni * 16 + l16; if (i > 48) i = 48;
        qfrag[ni] = *(const bf16x8*)(qh + i * 32 + quad * 8);
    }

    #pragma unroll
    for (int nt = 0; nt < 4; ++nt) {
        const int c0 = (w * 4 + nt) * 16;
        f32x4 acc[4] = {fzero, fzero, fzero, fzero};
        #pragma unroll
        for (int kk = 0; kk < 4; ++kk) {
            bf16x8 bfrag = *(const bf16x8*)(wkvt + (c0 + l16) * 128 + kk * 32 + quad * 8);
            #pragma unroll
            for (int mi = 0; mi < 4; ++mi)
                acc[mi] = __builtin_amdgcn_mfma_f32_16x16x32_bf16(afrag[mi][kk], bfrag, acc[mi], 0, 0, 0);
        }
        const int c = c0 + l16;
        const float bias = bkv[c];
        #pragma unroll
        for (int mi = 0; mi < 4; ++mi)
            #pragma unroll
            for (int r = 0; r < 4; ++r) {
                int tok = mi * 16 + quad * 4 + r;
                short val = cvt_bf16(acc[mi][r] + bias);
                if (c < 128) {
                    int hh = c >> 5, d = c & 31;
                    regA[hh * SLOT + tok * 40 + d] = val;
                } else {
                    int cv = c - 128, hh = cv >> 5, d = cv & 31;
                    vts[(hh * 32 + d) * 72 + tok] = val;
                }
            }
    }
    __syncthreads();

    // ---------------- Stage 2: St = K @ q^T (D[j][i]), softmax over j ----------------
    short* ksh = regA + h * SLOT;   // ks (stride 40), then ps overlay (stride 72)
    bf16x8 kfrag[4];
    #pragma unroll
    for (int mi = 0; mi < 4; ++mi)
        kfrag[mi] = *(const bf16x8*)(ksh + (mi * 16 + l16) * 40 + quad * 8);

    f32x4 sacc[4][4];   // [mi=j-tile][ni=i-tile]
    #pragma unroll
    for (int mi = 0; mi < 4; ++mi)
        #pragma unroll
        for (int ni = 0; ni < 4; ++ni) sacc[mi][ni] = fzero;
    #pragma unroll
    for (int ni = 0; ni < 4; ++ni)
        #pragma unroll
        for (int mi = 0; mi < 4; ++mi)
            sacc[mi][ni] = __builtin_amdgcn_mfma_f32_16x16x32_bf16(kfrag[mi], qfrag[ni], sacc[mi][ni], 0, 0, 0);

    #pragma unroll
    for (int ni = 0; ni < 4; ++ni) {
        int itok = ni * 16 + l16;
        int ic = itok > 48 ? 48 : itok;
        const float* bp = biasb + (h * 49 + ic) * 64;
        float v[16];
        #pragma unroll
        for (int mi = 0; mi < 4; ++mi) {
            float4 b4 = *(const float4*)(bp + mi * 16 + quad * 4);
            float bb[4] = {b4.x, b4.y, b4.z, b4.w};
            #pragma unroll
            for (int r = 0; r < 4; ++r) {
                int j = mi * 16 + quad * 4 + r;
                v[mi * 4 + r] = (j < 49) ? (sacc[mi][ni][r] + bb[r]) : -3.0e38f;
            }
        }
        float m = v[0];
        #pragma unroll
        for (int t = 1; t < 16; ++t) m = fmaxf(m, v[t]);
        m = fmaxf(m, __shfl_xor(m, 16, 64));
        m = fmaxf(m, __shfl_xor(m, 32, 64));
        float sum = 0.f;
        #pragma unroll
        for (int t = 0; t < 16; ++t) { float e = __expf(v[t] - m); v[t] = e; sum += e; }
        sum += __shfl_xor(sum, 16, 64);
        sum += __shfl_xor(sum, 32, 64);
        float inv = 1.0f / sum;
        if (itok < 52) {
            #pragma unroll
            for (int mi = 0; mi < 4; ++mi) {
                short p0 = cvt_bf16(v[mi * 4 + 0] * inv), p1 = cvt_bf16(v[mi * 4 + 1] * inv);
                short p2 = cvt_bf16(v[mi * 4 + 2] * inv), p3 = cvt_bf16(v[mi * 4 + 3] * inv);
                unsigned lo = (unsigned short)p0 | ((unsigned)(unsigned short)p1 << 16);
                unsigned hi = (unsigned short)p2 | ((unsigned)(unsigned short)p3 << 16);
                uint2 u; u.x = lo; u.y = hi;
                *(uint2*)(ksh + itok * 72 + mi * 16 + quad * 4) = u;
            }
        }
    }

    // ---------------- Stage 3: O = P @ V ----------------
    f32x4 oacc[4][2];
    #pragma unroll
    for (int mo = 0; mo < 4; ++mo)
        #pragma unroll
        for (int nt = 0; nt < 2; ++nt) oacc[mo][nt] = fzero;
    #pragma unroll
    for (int kk = 0; kk < 2; ++kk) {
        bf16x8 pfrag[4];
        #pragma unroll
        for (int mo = 0; mo < 4; ++mo)
            pfrag[mo] = *(const bf16x8*)(ksh + (mo * 16 + l16) * 72 + kk * 32 + quad * 8);
        #pragma unroll
        for (int nt = 0; nt < 2; ++nt) {
            bf16x8 vfrag = *(const bf16x8*)(vts + (h * 32 + nt * 16 + l16) * 72 + kk * 32 + quad * 8);
            #pragma unroll
            for (int mo = 0; mo < 4; ++mo)
                oacc[mo][nt] = __builtin_amdgcn_mfma_f32_16x16x32_bf16(pfrag[mo], vfrag, oacc[mo][nt], 0, 0, 0);
        }
    }
    __syncthreads();   // all waves done reading ps/vts regions os overlays

    #pragma unroll
    for (int mo = 0; mo < 4; ++mo)
        #pragma unroll
        for (int nt = 0; nt < 2; ++nt)
            #pragma unroll
            for (int r = 0; r < 4; ++r) {
                int tok = mo * 16 + quad * 4 + r;
                os[tok * 136 + h * 32 + nt * 16 + l16] = cvt_bf16(oacc[mo][nt][r]);
            }
    __syncthreads();

    // ---------------- Stage 4: out = O @ W_proj + b_proj ----------------
    bf16x8 ofrag[4][4];
    #pragma unroll
    for (int mi = 0; mi < 4; ++mi)
        #pragma unroll
        for (int kk = 0; kk < 4; ++kk)
            ofrag[mi][kk] = *(const bf16x8*)(os + (mi * 16 + l16) * 136 + kk * 32 + quad * 8);
    #pragma unroll
    for (int ct = 0; ct < 2; ++ct) {
        const int c0 = (w * 2 + ct) * 16;
        f32x4 pacc[4] = {fzero, fzero, fzero, fzero};
        #pragma unroll
        for (int kk = 0; kk < 4; ++kk) {
            bf16x8 wfrag = *(const bf16x8*)(wpt + (c0 + l16) * 128 + kk * 32 + quad * 8);
            #pragma unroll
            for (int mi = 0; mi < 4; ++mi)
                pacc[mi] = __builtin_amdgcn_mfma_f32_16x16x32_bf16(ofrag[mi][kk], wfrag, pacc[mi], 0, 0, 0);
        }
        const float bb = bpj[c0 + l16];
        #pragma unroll
        for (int mi = 0; mi < 4; ++mi)
            #pragma unroll
            for (int r = 0; r < 4; ++r) {
                int tok = mi * 16 + quad * 4 + r;
                if (tok < 49)
                    out[((long)b * 49 + tok) * 128 + c0 + l16] = pacc[mi][r] + bb;
            }
    }
}

extern "C" void kernel_launch(void* const* d_in, const int* in_sizes, int n_in,
                              void* d_out, int out_size, void* d_ws, size_t ws_size,
                              hipStream_t stream) {
    const float* x    = (const float*)d_in[0];
    const float* qg   = (const float*)d_in[1];
    const float* rbt  = (const float*)d_in[2];
    const float* wkv  = (const float*)d_in[3];
    const float* bkv  = (const float*)d_in[4];
    const float* wpj  = (const float*)d_in[5];
    const float* bpj  = (const float*)d_in[6];
    const int*   ridx = (const int*)d_in[7];
    short* ws = (short*)d_ws;

    const int prep_total = 32768 + 16384 + 100352 + 12544;
    prep_kernel<<<(prep_total + 255) / 256, 256, 0, stream>>>(qg, rbt, wkv, wpj, ridx, ws);
    win_attn_kernel<<<4096, 256, 0, stream>>>(x, ws, bkv, bpj, (float*)d_out);
}

// Round 3
// 300.101 us; speedup vs baseline: 1.0894x; 1.0323x over previous
//
#include <hip/hip_runtime.h>

#define SCALE 0.17677669529663687f

typedef __attribute__((ext_vector_type(8))) short bf16x8;
typedef __attribute__((ext_vector_type(4))) float f32x4;

__device__ inline short cvt_bf16(float f) {          // RNE (prep: weights/q)
    union { float f; unsigned u; } v; v.f = f;
    unsigned r = v.u + 0x7fffu + ((v.u >> 16) & 1u);
    return (short)(r >> 16);
}
__device__ inline short cvt_bf16_fast(float f) {     // round-up-ties, 2 ops
    union { float f; unsigned u; } v; v.f = f;
    return (short)((v.u + 0x8000u) >> 16);
}
__device__ inline unsigned pack_bf16x2(float f0, float f1) {
    union { float f; unsigned u; } a, b; a.f = f0; b.f = f1;
    return __builtin_amdgcn_perm(b.u + 0x8000u, a.u + 0x8000u, 0x07060302u);
}

// ws layout (short elements):
//   [0, 32768)        W_kv^T  bf16 [256][128]
//   [32768, 49152)    W_proj^T bf16 [128][128]
//   [49152, 450560)   q bf16 * SCALE, [64 img][4 h][49 n][32 d]
//   short 450560..    bias fp32 [4 h][49 i][64 jpad]
#define WS_WPT  32768
#define WS_QW   49152
#define WS_BIAS 450560

__global__ void prep_kernel(const float* __restrict__ qg,
                            const float* __restrict__ rbt,
                            const float* __restrict__ wkv,
                            const float* __restrict__ wpj,
                            const int*   __restrict__ ridx,
                            short* __restrict__ ws) {
    int i = blockIdx.x * 256 + threadIdx.x;
    if (i < 32768) {                       // W_kv^T
        int c = i >> 7, k = i & 127;
        ws[i] = cvt_bf16(wkv[k * 256 + c]);
        return;
    }
    i -= 32768;
    if (i < 16384) {                       // W_proj^T
        int c = i >> 7, k = i & 127;
        ws[WS_WPT + i] = cvt_bf16(wpj[k * 128 + c]);
        return;
    }
    i -= 16384;
    if (i < 100352) {                      // q * SCALE, 4 elems/thread
        float4 q4 = *(const float4*)(qg + (long)i * 4);
        unsigned lo = (unsigned)(unsigned short)cvt_bf16(q4.x * SCALE) |
                      ((unsigned)(unsigned short)cvt_bf16(q4.y * SCALE) << 16);
        unsigned hi = (unsigned)(unsigned short)cvt_bf16(q4.z * SCALE) |
                      ((unsigned)(unsigned short)cvt_bf16(q4.w * SCALE) << 16);
        uint2 u; u.x = lo; u.y = hi;
        *(uint2*)(ws + WS_QW + (long)i * 4) = u;
        return;
    }
    i -= 100352;
    if (i < 12544) {                       // bias padded [h][i][64]
        int h = i / 3136, rem = i % 3136, ir = rem >> 6, j = rem & 63;
        float* bias = (float*)(ws + WS_BIAS);
        bias[i] = (j < 49) ? rbt[ridx[ir * 49 + j] * 4 + h] : 0.f;
    }
}

// LDS (shorts), 39552 B total -> 4 blocks/CU:
//  P region [4 heads][3136]: K (64 rows x 40) overlaid by P (49 rows x 64, XOR-swizzled)
//  V^T @12544: [4*32 rows][56]   (toks 0..55; 56..63 never stored, P cols there = 0)
//  tail @19712: 64 zeroed shorts (guards last V row's b128 overread)
//  os  @0: [64][136] overlay for proj stage
#define PSLOT   3136
#define VOFF    12544
#define VSTR    56
#define SMEM_SZ 19776

__global__ __launch_bounds__(256, 4) void win_attn_kernel(
        const float* __restrict__ x,
        const short* __restrict__ ws,
        const float* __restrict__ bkv,
        const float* __restrict__ bpj,
        float* __restrict__ out) {
    const int b    = blockIdx.x;
    const int img  = b >> 6;
    const int tid  = threadIdx.x;
    const int w    = tid >> 6;
    const int lane = tid & 63;
    const int quad = lane >> 4;
    const int l16  = lane & 15;

    const short* wkvt  = ws;
    const short* wpt   = ws + WS_WPT;
    const short* qw    = ws + WS_QW;
    const float* biasb = (const float*)(ws + WS_BIAS);

    __shared__ __align__(16) short smem[SMEM_SZ];
    short* os = smem;

    if (tid < 64) smem[19712 + tid] = 0;   // zero tail guard (before barrier 1)

    const f32x4 fzero = {0.f, 0.f, 0.f, 0.f};
    const int h = w;

    // ---------------- Stage 1: kv = x[b] @ W_kv + b_kv ----------------
    bf16x8 afrag[4][4];
    const float* xb = x + (long)b * 49 * 128;
    #pragma unroll
    for (int mi = 0; mi < 4; ++mi) {
        int tok = mi * 16 + l16; if (tok > 48) tok = 48;
        #pragma unroll
        for (int kk = 0; kk < 4; ++kk) {
            const float* xr = xb + tok * 128 + kk * 32 + quad * 8;
            float4 a = *(const float4*)xr;
            float4 c = *(const float4*)(xr + 4);
            union { uint4 u; bf16x8 v; } pk;
            pk.u.x = pack_bf16x2(a.x, a.y);
            pk.u.y = pack_bf16x2(a.z, a.w);
            pk.u.z = pack_bf16x2(c.x, c.y);
            pk.u.w = pack_bf16x2(c.z, c.w);
            afrag[mi][kk] = pk.v;
        }
    }
    // prefetch q B-frags
    const short* qh = qw + (long)(img * 4 + h) * 49 * 32;
    bf16x8 qfrag[4];
    #pragma unroll
    for (int ni = 0; ni < 4; ++ni) {
        int i = ni * 16 + l16; if (i > 48) i = 48;
        qfrag[ni] = *(const bf16x8*)(qh + i * 32 + quad * 8);
    }

    #pragma unroll
    for (int nt = 0; nt < 4; ++nt) {
        const int c0 = (w * 4 + nt) * 16;
        f32x4 acc[4] = {fzero, fzero, fzero, fzero};
        #pragma unroll
        for (int kk = 0; kk < 4; ++kk) {
            bf16x8 bfrag = *(const bf16x8*)(wkvt + (c0 + l16) * 128 + kk * 32 + quad * 8);
            #pragma unroll
            for (int mi = 0; mi < 4; ++mi)
                acc[mi] = __builtin_amdgcn_mfma_f32_16x16x32_bf16(afrag[mi][kk], bfrag, acc[mi], 0, 0, 0);
        }
        const int c = c0 + l16;
        const float bv = bkv[c];
        if (c < 128) {                     // K: [h][tok stride 40][d]
            int hh = c >> 5, d = c & 31;
            short* kdst = smem + hh * PSLOT + d;
            #pragma unroll
            for (int mi = 0; mi < 4; ++mi)
                #pragma unroll
                for (int r = 0; r < 4; ++r) {
                    int tok = mi * 16 + quad * 4 + r;
                    kdst[tok * 40] = cvt_bf16_fast(acc[mi][r] + bv);
                }
        } else {                           // V^T: [h*32+d][tok], stride 56, packed b32
            int cv = c - 128, hh = cv >> 5, d = cv & 31;
            short* vdst = smem + VOFF + (hh * 32 + d) * VSTR;
            #pragma unroll
            for (int mi = 0; mi < 4; ++mi) {
                int tok0 = mi * 16 + quad * 4;
                if (tok0 < VSTR) {
                    *(unsigned*)(vdst + tok0)     = pack_bf16x2(acc[mi][0] + bv, acc[mi][1] + bv);
                    *(unsigned*)(vdst + tok0 + 2) = pack_bf16x2(acc[mi][2] + bv, acc[mi][3] + bv);
                }
            }
        }
    }
    __syncthreads();

    // ---------------- Stage 2: St = K @ q^T, softmax over j ----------------
    short* ksh = smem + h * PSLOT;
    bf16x8 kfrag[4];
    #pragma unroll
    for (int mi = 0; mi < 4; ++mi)
        kfrag[mi] = *(const bf16x8*)(ksh + (mi * 16 + l16) * 40 + quad * 8);

    f32x4 sacc[4][4];   // [mi=j-tile][ni=i-tile]
    #pragma unroll
    for (int mi = 0; mi < 4; ++mi)
        #pragma unroll
        for (int ni = 0; ni < 4; ++ni) sacc[mi][ni] = fzero;
    #pragma unroll
    for (int ni = 0; ni < 4; ++ni)
        #pragma unroll
        for (int mi = 0; mi < 4; ++mi)
            sacc[mi][ni] = __builtin_amdgcn_mfma_f32_16x16x32_bf16(kfrag[mi], qfrag[ni], sacc[mi][ni], 0, 0, 0);

    #pragma unroll
    for (int ni = 0; ni < 4; ++ni) {
        int itok = ni * 16 + l16;
        int ic = itok > 48 ? 48 : itok;
        const float* bp = biasb + (h * 49 + ic) * 64;
        float v[16];
        #pragma unroll
        for (int mi = 0; mi < 4; ++mi) {
            float4 b4 = *(const float4*)(bp + mi * 16 + quad * 4);
            float bb[4] = {b4.x, b4.y, b4.z, b4.w};
            #pragma unroll
            for (int r = 0; r < 4; ++r) {
                int j = mi * 16 + quad * 4 + r;
                v[mi * 4 + r] = (j < 49) ? (sacc[mi][ni][r] + bb[r]) : -3.0e38f;
            }
        }
        float m = v[0];
        #pragma unroll
        for (int t = 1; t < 16; ++t) m = fmaxf(m, v[t]);
        m = fmaxf(m, __shfl_xor(m, 16, 64));
        m = fmaxf(m, __shfl_xor(m, 32, 64));
        float sum = 0.f;
        #pragma unroll
        for (int t = 0; t < 16; ++t) { float e = __expf(v[t] - m); v[t] = e; sum += e; }
        sum += __shfl_xor(sum, 16, 64);
        sum += __shfl_xor(sum, 32, 64);
        float inv = 1.0f / sum;
        if (itok < 49) {                   // P: swizzled, stride 64
            #pragma unroll
            for (int mi = 0; mi < 4; ++mi) {
                int jo8 = mi * 2 + (quad >> 1);
                int off = itok * 64 + ((jo8 ^ (itok & 7)) << 3) + ((quad & 1) << 2);
                uint2 u;
                u.x = pack_bf16x2(v[mi * 4 + 0] * inv, v[mi * 4 + 1] * inv);
                u.y = pack_bf16x2(v[mi * 4 + 2] * inv, v[mi * 4 + 3] * inv);
                *(uint2*)(ksh + off) = u;
            }
        }
    }

    // ---------------- Stage 3: O = P @ V ----------------
    f32x4 oacc[4][2];
    #pragma unroll
    for (int mo = 0; mo < 4; ++mo)
        #pragma unroll
        for (int nt = 0; nt < 2; ++nt) oacc[mo][nt] = fzero;
    #pragma unroll
    for (int kk = 0; kk < 2; ++kk) {
        bf16x8 pfrag[4];
        #pragma unroll
        for (int mo = 0; mo < 4; ++mo) {
            int row = mo * 16 + l16; if (row > 48) row = 48;
            int jo8 = kk * 4 + quad;
            pfrag[mo] = *(const bf16x8*)(ksh + row * 64 + ((jo8 ^ (row & 7)) << 3));
        }
        #pragma unroll
        for (int nt = 0; nt < 2; ++nt) {
            bf16x8 vfrag = *(const bf16x8*)(smem + VOFF + (h * 32 + nt * 16 + l16) * VSTR + kk * 32 + quad * 8);
            #pragma unroll
            for (int mo = 0; mo < 4; ++mo)
                oacc[mo][nt] = __builtin_amdgcn_mfma_f32_16x16x32_bf16(pfrag[mo], vfrag, oacc[mo][nt], 0, 0, 0);
        }
    }
    __syncthreads();   // all waves done reading P/V before os overlay

    #pragma unroll
    for (int mo = 0; mo < 4; ++mo)
        #pragma unroll
        for (int nt = 0; nt < 2; ++nt)
            #pragma unroll
            for (int r = 0; r < 4; ++r) {
                int tok = mo * 16 + quad * 4 + r;
                os[tok * 136 + h * 32 + nt * 16 + l16] = cvt_bf16_fast(oacc[mo][nt][r]);
            }
    __syncthreads();

    // ---------------- Stage 4: out = O @ W_proj + b_proj ----------------
    bf16x8 ofrag[4][4];
    #pragma unroll
    for (int mi = 0; mi < 4; ++mi)
        #pragma unroll
        for (int kk = 0; kk < 4; ++kk)
            ofrag[mi][kk] = *(const bf16x8*)(os + (mi * 16 + l16) * 136 + kk * 32 + quad * 8);
    #pragma unroll
    for (int ct = 0; ct < 2; ++ct) {
        const int c0 = (w * 2 + ct) * 16;
        f32x4 pacc[4] = {fzero, fzero, fzero, fzero};
        #pragma unroll
        for (int kk = 0; kk < 4; ++kk) {
            bf16x8 wfrag = *(const bf16x8*)(wpt + (c0 + l16) * 128 + kk * 32 + quad * 8);
            #pragma unroll
            for (int mi = 0; mi < 4; ++mi)
                pacc[mi] = __builtin_amdgcn_mfma_f32_16x16x32_bf16(ofrag[mi][kk], wfrag, pacc[mi], 0, 0, 0);
        }
        const float bb = bpj[c0 + l16];
        #pragma unroll
        for (int mi = 0; mi < 4; ++mi)
            #pragma unroll
            for (int r = 0; r < 4; ++r) {
                int tok = mi * 16 + quad * 4 + r;
                if (tok < 49)
                    out[((long)b * 49 + tok) * 128 + c0 + l16] = pacc[mi][r] + bb;
            }
    }
}

extern "C" void kernel_launch(void* const* d_in, const int* in_sizes, int n_in,
                              void* d_out, int out_size, void* d_ws, size_t ws_size,
                              hipStream_t stream) {
    const float* x    = (const float*)d_in[0];
    const float* qg   = (const float*)d_in[1];
    const float* rbt  = (const float*)d_in[2];
    const float* wkv  = (const float*)d_in[3];
    const float* bkv  = (const float*)d_in[4];
    const float* wpj  = (const float*)d_in[5];
    const float* bpj  = (const float*)d_in[6];
    const int*   ridx = (const int*)d_in[7];
    short* ws = (short*)d_ws;

    const int prep_total = 32768 + 16384 + 100352 + 12544;
    prep_kernel<<<(prep_total + 255) / 256, 256, 0, stream>>>(qg, rbt, wkv, wpj, ridx, ws);
    win_attn_kernel<<<4096, 256, 0, stream>>>(x, ws, bkv, bpj, (float*)d_out);
}